// Round 1
// baseline (80.708 us; speedup 1.0000x reference)
//
#include <hip/hip_runtime.h>
#include <math.h>

#define B_ 4
#define N_ 32768
#define M_ 8192
#define K_ 16
#define D_ 64
#define O_ 64

// ---------------------------------------------------------------------------
// Kernel A: fused GEMM producing
//   G[row][o]  = dot(x[row][:], W[o][0:64])                    for row <  B*N
//   C[row'][o] = dot(xs[row'][:], W[o][64:128]-W[o][0:64]) + b[o]
// Grid: 640 blocks x 256 threads. Blocks 0..511 -> G rows, 512..639 -> C rows.
// Each block handles 256 consecutive rows; thread = (lane -> 4 rows, wave -> o-quarter).
// Per thread: acc[4 rows][16 o] in VGPRs; W quarter read from LDS as broadcast
// float4 (16 FMAs amortize each ds_read_b128).
// ---------------------------------------------------------------------------
__global__ __launch_bounds__(256)
void gemm_gc(const float* __restrict__ x, const float* __restrict__ xs,
             const float* __restrict__ W, const float* __restrict__ bias,
             float* __restrict__ G, float* __restrict__ C) {
    __shared__ float wlds[64 * 64];
    __shared__ float blds[64];

    const int tid = threadIdx.x;
    const int blk = blockIdx.x;
    const bool cmode = (blk >= (B_ * N_) / 256);   // >= 512

    // ---- stage W (or Wdiff) into LDS: wlds[o][d], o-major rows of 64 floats
    {
        int o  = tid >> 2;            // 0..63
        int dc = (tid & 3) * 16;      // 0,16,32,48
        const float* wrow = W + o * 128;
        #pragma unroll
        for (int j = 0; j < 16; j += 4) {
            float4 w1 = *(const float4*)(wrow + dc + j);
            if (cmode) {
                float4 w2 = *(const float4*)(wrow + 64 + dc + j);
                w1.x = w2.x - w1.x; w1.y = w2.y - w1.y;
                w1.z = w2.z - w1.z; w1.w = w2.w - w1.w;
            }
            *(float4*)(&wlds[o * 64 + dc + j]) = w1;
        }
        if (tid < 64) blds[tid] = bias[tid];
    }
    __syncthreads();

    const int lane = tid & 63;
    const int og   = tid >> 6;                        // o-quarter 0..3
    const long row0 = (long)blk * 256 + lane * 4;     // 4 consecutive rows

    const float* src = cmode ? (xs + (row0 - (long)B_ * N_) * 64)
                             : (x  + row0 * 64);

    float acc[4][16];
    #pragma unroll
    for (int r = 0; r < 4; ++r)
        #pragma unroll
        for (int j = 0; j < 16; ++j)
            acc[r][j] = cmode ? blds[og * 16 + j] : 0.0f;

    for (int d4 = 0; d4 < 16; ++d4) {
        float4 xc[4];
        #pragma unroll
        for (int r = 0; r < 4; ++r)
            xc[r] = *(const float4*)(src + r * 64 + d4 * 4);

        #pragma unroll
        for (int j = 0; j < 16; ++j) {
            float4 w = *(const float4*)(&wlds[(og * 16 + j) * 64 + d4 * 4]);
            #pragma unroll
            for (int r = 0; r < 4; ++r) {
                acc[r][j] = fmaf(xc[r].x, w.x, acc[r][j]);
                acc[r][j] = fmaf(xc[r].y, w.y, acc[r][j]);
                acc[r][j] = fmaf(xc[r].z, w.z, acc[r][j]);
                acc[r][j] = fmaf(xc[r].w, w.w, acc[r][j]);
            }
        }
    }

    float* dst = cmode ? (C + (row0 - (long)B_ * N_) * 64 + og * 16)
                       : (G + row0 * 64 + og * 16);
    #pragma unroll
    for (int r = 0; r < 4; ++r) {
        #pragma unroll
        for (int j4 = 0; j4 < 4; ++j4) {
            float4 v = make_float4(acc[r][j4 * 4 + 0], acc[r][j4 * 4 + 1],
                                   acc[r][j4 * 4 + 2], acc[r][j4 * 4 + 3]);
            *(float4*)(dst + r * 64 + j4 * 4) = v;
        }
    }
}

// ---------------------------------------------------------------------------
// Kernel B: out[b,o,m] = relu( max_k G[b, idx[b,m,k], o] + C[b,m,o] )
// Grid: 512 blocks x 256 threads. Block = 64 consecutive m of one batch.
// thread: m = tid&63, o-quarter = tid>>6 (16 outputs). Stores are coalesced
// across lanes (consecutive m, same o).
// ---------------------------------------------------------------------------
__global__ __launch_bounds__(256)
void gather_max(const int* __restrict__ idx, const float* __restrict__ G,
                const float* __restrict__ C, float* __restrict__ out) {
    const int tid = threadIdx.x;
    const int blk = blockIdx.x;          // 0..511
    const int bm0 = blk * 64;            // base of 64 (b*M+m) pairs
    const int b   = blk >> 7;            // 128 blocks per batch (M/64)
    const int m   = tid & 63;
    const int og  = tid >> 6;

    // own idx row: 16 ints = 64B contiguous
    const int* ip = idx + (size_t)(bm0 + m) * K_;
    int4 rows[4];
    #pragma unroll
    for (int k4 = 0; k4 < 4; ++k4) rows[k4] = ((const int4*)ip)[k4];

    const float* Gb = G + (size_t)b * N_ * 64 + og * 16;

    float gmax[16];
    #pragma unroll
    for (int j = 0; j < 16; ++j) gmax[j] = -INFINITY;

    #pragma unroll
    for (int k4 = 0; k4 < 4; ++k4) {
        int r[4] = {rows[k4].x, rows[k4].y, rows[k4].z, rows[k4].w};
        #pragma unroll
        for (int kk = 0; kk < 4; ++kk) {
            const float* g = Gb + (size_t)r[kk] * 64;
            #pragma unroll
            for (int j4 = 0; j4 < 4; ++j4) {
                float4 v = *(const float4*)(g + j4 * 4);
                gmax[j4 * 4 + 0] = fmaxf(gmax[j4 * 4 + 0], v.x);
                gmax[j4 * 4 + 1] = fmaxf(gmax[j4 * 4 + 1], v.y);
                gmax[j4 * 4 + 2] = fmaxf(gmax[j4 * 4 + 2], v.z);
                gmax[j4 * 4 + 3] = fmaxf(gmax[j4 * 4 + 3], v.w);
            }
        }
    }

    const float* c = C + (size_t)(bm0 + m) * 64 + og * 16;
    float cv[16];
    #pragma unroll
    for (int j4 = 0; j4 < 4; ++j4) {
        float4 v = *(const float4*)(c + j4 * 4);
        cv[j4 * 4 + 0] = v.x; cv[j4 * 4 + 1] = v.y;
        cv[j4 * 4 + 2] = v.z; cv[j4 * 4 + 3] = v.w;
    }

    const int mglob = ((blk & 127) << 6) + m;    // m within batch
    float* ob = out + ((size_t)b * 64 + og * 16) * M_ + mglob;
    #pragma unroll
    for (int j = 0; j < 16; ++j) {
        float v = gmax[j] + cv[j];
        ob[(size_t)j * M_] = v > 0.0f ? v : 0.0f;
    }
}

// ---------------------------------------------------------------------------
// Naive exact fallback (only if ws_size < 42MB): one thread per output elem.
// ---------------------------------------------------------------------------
__global__ void naive_all(const float* __restrict__ x, const float* __restrict__ xs,
                          const int* __restrict__ idx, const float* __restrict__ W,
                          const float* __restrict__ bias, float* __restrict__ out) {
    size_t t = (size_t)blockIdx.x * 256 + threadIdx.x;
    if (t >= (size_t)B_ * O_ * M_) return;
    int m = (int)(t % M_);
    int o = (int)((t / M_) % O_);
    int b = (int)(t / ((size_t)M_ * O_));
    const float* xb = x + (size_t)b * N_ * D_;
    const float* c  = xs + ((size_t)b * M_ + m) * D_;
    const int*   id = idx + ((size_t)b * M_ + m) * K_;
    const float* w1 = W + o * 128;
    const float* w2 = w1 + 64;
    float best = -INFINITY;
    for (int k = 0; k < K_; ++k) {
        const float* g = xb + (size_t)id[k] * D_;
        float s = bias[o];
        for (int d = 0; d < D_; ++d)
            s += (g[d] - c[d]) * w1[d] + c[d] * w2[d];
        best = fmaxf(best, s);
    }
    out[t] = best > 0.0f ? best : 0.0f;
}

extern "C" void kernel_launch(void* const* d_in, const int* in_sizes, int n_in,
                              void* d_out, int out_size, void* d_ws, size_t ws_size,
                              hipStream_t stream) {
    const float* x    = (const float*)d_in[0];
    const float* xs   = (const float*)d_in[1];
    const int*   idx  = (const int*)d_in[2];
    const float* W    = (const float*)d_in[3];
    const float* bias = (const float*)d_in[4];
    float* out = (float*)d_out;

    const size_t needG = (size_t)B_ * N_ * O_ * sizeof(float);  // 33.55 MB
    const size_t needC = (size_t)B_ * M_ * O_ * sizeof(float);  //  8.39 MB

    if (ws_size < needG + needC) {
        size_t total = (size_t)B_ * O_ * M_;
        naive_all<<<(int)((total + 255) / 256), 256, 0, stream>>>(x, xs, idx, W, bias, out);
        return;
    }

    float* G = (float*)d_ws;
    float* C = G + (size_t)B_ * N_ * O_;

    gemm_gc<<<(B_ * N_ + B_ * M_) / 256, 256, 0, stream>>>(x, xs, W, bias, G, C);
    gather_max<<<(B_ * M_) / 64, 256, 0, stream>>>(idx, G, C, out);
}

// Round 2
// 72.050 us; speedup vs baseline: 1.1202x; 1.1202x over previous
//
#include <hip/hip_runtime.h>
#include <hip/hip_fp16.h>
#include <math.h>

#define B_ 4
#define N_ 32768
#define M_ 8192
#define K_ 16
#define D_ 64
#define O_ 64

// ---------------------------------------------------------------------------
// Kernel A: G[b][og][n][16] (fp16) = x[b,n] . W1[og*16+j]
//           C[b][og][m][16] (fp32) = xs[b,m] . (W2-W1)[og*16+j] + bias
// Block = 256 threads, 128 rows. Wave = one o-quarter (W reads are wave-
// uniform LDS broadcasts). Lane l handles rows l and l+64 of the tile.
// x tile staged coalesced into LDS padded to 65 floats/row (2-way = free).
// ---------------------------------------------------------------------------
__global__ __launch_bounds__(256)
void gemm_gc(const float* __restrict__ x, const float* __restrict__ xs,
             const float* __restrict__ W, const float* __restrict__ bias,
             __half* __restrict__ G, float* __restrict__ C) {
    __shared__ float wlds[64 * 64];    // [o][d], W1 or (W2-W1)
    __shared__ float xlds[128 * 65];   // padded rows
    __shared__ float blds[64];

    const int tid = threadIdx.x;
    const int blk = blockIdx.x;
    const bool cmode = (blk >= (B_ * N_) / 128);   // >= 1024

    // ---- stage W (or Wdiff) + bias
    {
        int o  = tid >> 2;
        int dc = (tid & 3) * 16;
        const float* wrow = W + o * 128;
        #pragma unroll
        for (int j = 0; j < 16; j += 4) {
            float4 w1 = *(const float4*)(wrow + dc + j);
            if (cmode) {
                float4 w2 = *(const float4*)(wrow + 64 + dc + j);
                w1.x = w2.x - w1.x; w1.y = w2.y - w1.y;
                w1.z = w2.z - w1.z; w1.w = w2.w - w1.w;
            }
            *(float4*)(&wlds[o * 64 + dc + j]) = w1;
        }
        if (tid < 64) blds[tid] = bias[tid];
    }

    // ---- stage 128x64 x-tile, fully coalesced
    const long rb = cmode ? ((long)blk - (B_ * N_) / 128) * 128 : (long)blk * 128;
    const float* src = cmode ? (xs + rb * 64) : (x + rb * 64);
    #pragma unroll
    for (int i = 0; i < 8; ++i) {
        int f = i * 256 + tid;              // float4 index within tile
        int r = f >> 4, c4 = f & 15;
        float4 v = ((const float4*)src)[f];
        *(float4*)(&xlds[r * 65 + c4 * 4]) = v;
    }
    __syncthreads();

    const int og = tid >> 6;    // wave id = o-quarter
    const int l  = tid & 63;

    float acc[2][16];
    #pragma unroll
    for (int r = 0; r < 2; ++r)
        #pragma unroll
        for (int j = 0; j < 16; ++j)
            acc[r][j] = cmode ? blds[og * 16 + j] : 0.0f;

    const float* x0 = &xlds[l * 65];
    const float* x1 = &xlds[(l + 64) * 65];
    const float* wq = &wlds[(og * 16) * 64];

    for (int d4 = 0; d4 < 16; ++d4) {
        float4 a0 = *(const float4*)(x0 + d4 * 4);
        float4 a1 = *(const float4*)(x1 + d4 * 4);
        #pragma unroll
        for (int j = 0; j < 16; ++j) {
            float4 w = *(const float4*)(wq + j * 64 + d4 * 4);
            acc[0][j] = fmaf(a0.x, w.x, acc[0][j]);
            acc[0][j] = fmaf(a0.y, w.y, acc[0][j]);
            acc[0][j] = fmaf(a0.z, w.z, acc[0][j]);
            acc[0][j] = fmaf(a0.w, w.w, acc[0][j]);
            acc[1][j] = fmaf(a1.x, w.x, acc[1][j]);
            acc[1][j] = fmaf(a1.y, w.y, acc[1][j]);
            acc[1][j] = fmaf(a1.z, w.z, acc[1][j]);
            acc[1][j] = fmaf(a1.w, w.w, acc[1][j]);
        }
    }

    if (!cmode) {
        const int b  = (int)(rb >> 15);          // rb / N_
        const int n0 = (int)(rb & (N_ - 1));
        #pragma unroll
        for (int r = 0; r < 2; ++r) {
            __half2 h[8];
            #pragma unroll
            for (int e = 0; e < 8; ++e)
                h[e] = __floats2half2_rn(acc[r][2 * e], acc[r][2 * e + 1]);
            __half* gp = G + ((((size_t)b * 4 + og) * N_) + (n0 + l + r * 64)) * 16;
            *(int4*)(gp)     = *(int4*)&h[0];
            *(int4*)(gp + 8) = *(int4*)&h[4];
        }
    } else {
        const int b  = (int)(rb >> 13);          // rb / M_
        const int m0 = (int)(rb & (M_ - 1));
        #pragma unroll
        for (int r = 0; r < 2; ++r) {
            float* cp = C + ((((size_t)b * 4 + og) * M_) + (m0 + l + r * 64)) * 16;
            #pragma unroll
            for (int j4 = 0; j4 < 4; ++j4)
                *(float4*)(cp + j4 * 4) = make_float4(acc[r][j4 * 4 + 0], acc[r][j4 * 4 + 1],
                                                      acc[r][j4 * 4 + 2], acc[r][j4 * 4 + 3]);
        }
    }
}

// ---------------------------------------------------------------------------
// Kernel B: out[b, og8*8+j, m] = relu( max_k G[b, og8>>1, idx[b,m,k]][(og8&1)*8+j]
//                                      + C[b, og8>>1, m][(og8&1)*8+j] )
// Block = 256 threads = 32 m x 8 og8 (8 outputs/thread, 16B per gather).
// 1024 blocks -> 4096 waves for gather-latency hiding.
// ---------------------------------------------------------------------------
__global__ __launch_bounds__(256)
void gather_max(const int* __restrict__ idx, const __half* __restrict__ G,
                const float* __restrict__ C, float* __restrict__ out) {
    const int tid = threadIdx.x;
    const int blk = blockIdx.x;            // 0..1023
    const int b   = blk >> 8;              // 256 blocks per batch
    const int mib = ((blk & 255) << 5) + (tid & 31);   // m within batch
    const int og8 = tid >> 5;              // 0..7
    const int og  = og8 >> 1;
    const int half8 = (og8 & 1) * 8;

    const int* ip = idx + (((size_t)b * M_) + mib) * K_;
    int4 rows[4];
    #pragma unroll
    for (int k4 = 0; k4 < 4; ++k4) rows[k4] = ((const int4*)ip)[k4];

    const __half* Gb = G + ((size_t)b * 4 + og) * N_ * 16 + half8;

    float gmax[8];
    #pragma unroll
    for (int j = 0; j < 8; ++j) gmax[j] = -INFINITY;

    #pragma unroll
    for (int k4 = 0; k4 < 4; ++k4) {
        int r[4] = {rows[k4].x, rows[k4].y, rows[k4].z, rows[k4].w};
        #pragma unroll
        for (int kk = 0; kk < 4; ++kk) {
            int4 u = *(const int4*)(Gb + (size_t)r[kk] * 16);
            const __half2* h = (const __half2*)&u;
            #pragma unroll
            for (int e = 0; e < 4; ++e) {
                float2 f = __half22float2(h[e]);
                gmax[2 * e]     = fmaxf(gmax[2 * e], f.x);
                gmax[2 * e + 1] = fmaxf(gmax[2 * e + 1], f.y);
            }
        }
    }

    const float* cp = C + (((size_t)b * 4 + og) * M_ + mib) * 16 + half8;
    float cv[8];
    #pragma unroll
    for (int j4 = 0; j4 < 2; ++j4) {
        float4 v = *(const float4*)(cp + j4 * 4);
        cv[j4 * 4 + 0] = v.x; cv[j4 * 4 + 1] = v.y;
        cv[j4 * 4 + 2] = v.z; cv[j4 * 4 + 3] = v.w;
    }

    float* ob = out + ((size_t)b * 64 + og8 * 8) * M_ + mib;
    #pragma unroll
    for (int j = 0; j < 8; ++j) {
        float v = gmax[j] + cv[j];
        ob[(size_t)j * M_] = v > 0.0f ? v : 0.0f;
    }
}

// ---------------------------------------------------------------------------
// Naive exact fallback (only if ws too small).
// ---------------------------------------------------------------------------
__global__ void naive_all(const float* __restrict__ x, const float* __restrict__ xs,
                          const int* __restrict__ idx, const float* __restrict__ W,
                          const float* __restrict__ bias, float* __restrict__ out) {
    size_t t = (size_t)blockIdx.x * 256 + threadIdx.x;
    if (t >= (size_t)B_ * O_ * M_) return;
    int m = (int)(t % M_);
    int o = (int)((t / M_) % O_);
    int b = (int)(t / ((size_t)M_ * O_));
    const float* xb = x + (size_t)b * N_ * D_;
    const float* c  = xs + ((size_t)b * M_ + m) * D_;
    const int*   id = idx + ((size_t)b * M_ + m) * K_;
    const float* w1 = W + o * 128;
    const float* w2 = w1 + 64;
    float best = -INFINITY;
    for (int k = 0; k < K_; ++k) {
        const float* g = xb + (size_t)id[k] * D_;
        float s = bias[o];
        for (int d = 0; d < D_; ++d)
            s += (g[d] - c[d]) * w1[d] + c[d] * w2[d];
        best = fmaxf(best, s);
    }
    out[t] = best > 0.0f ? best : 0.0f;
}

extern "C" void kernel_launch(void* const* d_in, const int* in_sizes, int n_in,
                              void* d_out, int out_size, void* d_ws, size_t ws_size,
                              hipStream_t stream) {
    const float* x    = (const float*)d_in[0];
    const float* xs   = (const float*)d_in[1];
    const int*   idx  = (const int*)d_in[2];
    const float* W    = (const float*)d_in[3];
    const float* bias = (const float*)d_in[4];
    float* out = (float*)d_out;

    const size_t needG = (size_t)B_ * 4 * N_ * 16 * sizeof(__half);  // 16.78 MB
    const size_t needC = (size_t)B_ * 4 * M_ * 16 * sizeof(float);   //  8.39 MB

    if (ws_size < needG + needC) {
        size_t total = (size_t)B_ * O_ * M_;
        naive_all<<<(int)((total + 255) / 256), 256, 0, stream>>>(x, xs, idx, W, bias, out);
        return;
    }

    __half* G = (__half*)d_ws;
    float*  C = (float*)((char*)d_ws + needG);

    gemm_gc<<<(B_ * N_ + B_ * M_) / 128, 256, 0, stream>>>(x, xs, W, bias, G, C);
    gather_max<<<(B_ * M_) / 32, 256, 0, stream>>>(idx, G, C, out);
}

// Round 3
// 59.765 us; speedup vs baseline: 1.3504x; 1.2056x over previous
//
#include <hip/hip_runtime.h>
#include <hip/hip_fp16.h>
#include <math.h>

#define B_ 4
#define N_ 32768
#define M_ 8192
#define K_ 16
#define D_ 64
#define O_ 64

typedef __attribute__((ext_vector_type(8))) short bf16x8;
typedef __attribute__((ext_vector_type(4))) float f32x4;

// float -> bf16 bits, round-to-nearest-even (inputs are finite normals)
static __device__ __forceinline__ short f2bf(float f) {
    unsigned u = __float_as_uint(f);
    u += 0x7fffu + ((u >> 16) & 1u);
    return (short)(u >> 16);
}

// ---------------------------------------------------------------------------
// Kernel A (MFMA, no LDS):
//   G[b*N+n][64] fp16 = x-row . W1       (permuted col order: pos p = o-col
//   C[b*M+m][64] fp16 = xs-row . (W2-W1) + bias     where o = (p&3)*16+(p>>2))
// Wave = 1 job of 64 rows (4 tiles of 16). Fragments loaded straight from
// global in MFMA lane layout: lane l -> row (l&15), k-chunk (l>>4)*8.
// ---------------------------------------------------------------------------
__global__ __launch_bounds__(256)
void gemm_gc(const float* __restrict__ x, const float* __restrict__ xs,
             const float* __restrict__ W, const float* __restrict__ bias,
             __half* __restrict__ G, __half* __restrict__ C) {
    const int tid = threadIdx.x;
    const int l   = tid & 63;
    const int lr  = l & 15;          // A-row / B-col within tile
    const int kg  = l >> 4;          // k-group (8 consecutive k each)
    const int job = blockIdx.x * 4 + (tid >> 6);
    const bool cmode = job >= (B_ * N_) / 64;    // jobs 2048..2559

    // ---- B fragments: bf[s][t] covers k = s*32 + kg*8 + 0..7, o = t*16 + lr
    bf16x8 bf[2][4];
    float  binit[4] = {0.f, 0.f, 0.f, 0.f};
    #pragma unroll
    for (int t = 0; t < 4; ++t) {
        #pragma unroll
        for (int s = 0; s < 2; ++s) {
            const float* wp = W + (size_t)(t * 16 + lr) * 128 + s * 32 + kg * 8;
            float4 f0 = *(const float4*)wp;
            float4 f1 = *(const float4*)(wp + 4);
            if (cmode) {
                float4 g0 = *(const float4*)(wp + 64);
                float4 g1 = *(const float4*)(wp + 68);
                f0.x = g0.x - f0.x; f0.y = g0.y - f0.y;
                f0.z = g0.z - f0.z; f0.w = g0.w - f0.w;
                f1.x = g1.x - f1.x; f1.y = g1.y - f1.y;
                f1.z = g1.z - f1.z; f1.w = g1.w - f1.w;
            }
            bf16x8 v;
            v[0] = f2bf(f0.x); v[1] = f2bf(f0.y); v[2] = f2bf(f0.z); v[3] = f2bf(f0.w);
            v[4] = f2bf(f1.x); v[5] = f2bf(f1.y); v[6] = f2bf(f1.z); v[7] = f2bf(f1.w);
            bf[s][t] = v;
        }
    }
    if (cmode) {
        #pragma unroll
        for (int t = 0; t < 4; ++t) binit[t] = bias[t * 16 + lr];
    }

    const long rows0 = (cmode ? (long)(job - (B_ * N_) / 64) : (long)job) * 64;
    const float* src = cmode ? xs : x;
    __half* dst = cmode ? C : G;

    for (int i = 0; i < 4; ++i) {
        const long r0 = rows0 + i * 16;

        // A fragments for this 16-row tile
        bf16x8 af[2];
        #pragma unroll
        for (int s = 0; s < 2; ++s) {
            const float* xp = src + (size_t)(r0 + lr) * 64 + s * 32 + kg * 8;
            float4 f0 = *(const float4*)xp;
            float4 f1 = *(const float4*)(xp + 4);
            bf16x8 v;
            v[0] = f2bf(f0.x); v[1] = f2bf(f0.y); v[2] = f2bf(f0.z); v[3] = f2bf(f0.w);
            v[4] = f2bf(f1.x); v[5] = f2bf(f1.y); v[6] = f2bf(f1.z); v[7] = f2bf(f1.w);
            af[s] = v;
        }

        f32x4 acc[4];
        #pragma unroll
        for (int t = 0; t < 4; ++t) {
            f32x4 a = {binit[t], binit[t], binit[t], binit[t]};
            a = __builtin_amdgcn_mfma_f32_16x16x32_bf16(af[0], bf[0][t], a, 0, 0, 0);
            a = __builtin_amdgcn_mfma_f32_16x16x32_bf16(af[1], bf[1][t], a, 0, 0, 0);
            acc[t] = a;
        }

        // D layout: lane holds rows (kg*4 + r), col lr, for 4 o-tiles t.
        // Permuted row storage: element index lr*4 + t  -> 4 contiguous fp16.
        #pragma unroll
        for (int r = 0; r < 4; ++r) {
            unsigned lo = (unsigned)__half_as_ushort(__float2half(acc[0][r]))
                        | ((unsigned)__half_as_ushort(__float2half(acc[1][r])) << 16);
            unsigned hi = (unsigned)__half_as_ushort(__float2half(acc[2][r]))
                        | ((unsigned)__half_as_ushort(__float2half(acc[3][r])) << 16);
            __half* hp = dst + (size_t)(r0 + kg * 4 + r) * 64 + lr * 4;
            int2 pv; pv.x = (int)lo; pv.y = (int)hi;
            *(int2*)hp = pv;
        }
    }
}

// ---------------------------------------------------------------------------
// Kernel B: wave per m (8 m's per wave, 32 m per block).
// Lane j gathers G[b, idx[m,k]][j] (2B; wave-load = exactly one 128B line),
// max over k, + C, relu; transpose via LDS; coalesced float4 stores to
// out[b][o][m] with o = (j&3)*16 + (j>>2) (un-permutes A's column order).
// ---------------------------------------------------------------------------
__global__ __launch_bounds__(256)
void gather_max(const int* __restrict__ idx, const __half* __restrict__ G,
                const __half* __restrict__ C, float* __restrict__ out) {
    __shared__ float ldsT[64 * 33];
    const int tid = threadIdx.x;
    const int blk = blockIdx.x;          // 0..1023
    const int bb  = blk >> 8;            // 256 blocks per batch
    const int m0  = (blk & 255) * 32;
    const int j   = tid & 63;
    const int wv  = tid >> 6;
    const int o_orig = (j & 3) * 16 + (j >> 2);

    const __half* Gb = G + (size_t)bb * N_ * 64 + j;

    #pragma unroll
    for (int mm = 0; mm < 8; ++mm) {
        const int mloc = wv * 8 + mm;
        const size_t mrow = (size_t)bb * M_ + (m0 + mloc);
        const int* ip = idx + mrow * 16;
        int4 q0 = ((const int4*)ip)[0];
        int4 q1 = ((const int4*)ip)[1];
        int4 q2 = ((const int4*)ip)[2];
        int4 q3 = ((const int4*)ip)[3];
        int rr[16] = {q0.x, q0.y, q0.z, q0.w, q1.x, q1.y, q1.z, q1.w,
                      q2.x, q2.y, q2.z, q2.w, q3.x, q3.y, q3.z, q3.w};
        float best = -INFINITY;
        #pragma unroll
        for (int k = 0; k < 16; ++k)
            best = fmaxf(best, __half2float(Gb[(size_t)rr[k] * 64]));
        float cv = __half2float(C[mrow * 64 + j]);
        float r = best + cv;
        ldsT[o_orig * 33 + mloc] = r > 0.f ? r : 0.f;
    }
    __syncthreads();

    // out: thread t -> o = t>>2, 8 consecutive m at (t&3)*8
    const int o  = tid >> 2;
    const int ms = (tid & 3) * 8;
    float v[8];
    #pragma unroll
    for (int i2 = 0; i2 < 8; ++i2) v[i2] = ldsT[o * 33 + ms + i2];
    float4 v0 = make_float4(v[0], v[1], v[2], v[3]);
    float4 v1 = make_float4(v[4], v[5], v[6], v[7]);
    float* op = out + ((size_t)bb * 64 + o) * M_ + m0 + ms;
    *(float4*)op = v0;
    *(float4*)(op + 4) = v1;
}

// ---------------------------------------------------------------------------
// Naive exact fallback (only if ws too small).
// ---------------------------------------------------------------------------
__global__ void naive_all(const float* __restrict__ x, const float* __restrict__ xs,
                          const int* __restrict__ idx, const float* __restrict__ W,
                          const float* __restrict__ bias, float* __restrict__ out) {
    size_t t = (size_t)blockIdx.x * 256 + threadIdx.x;
    if (t >= (size_t)B_ * O_ * M_) return;
    int m = (int)(t % M_);
    int o = (int)((t / M_) % O_);
    int b = (int)(t / ((size_t)M_ * O_));
    const float* xb = x + (size_t)b * N_ * D_;
    const float* c  = xs + ((size_t)b * M_ + m) * D_;
    const int*   id = idx + ((size_t)b * M_ + m) * K_;
    const float* w1 = W + o * 128;
    const float* w2 = w1 + 64;
    float best = -INFINITY;
    for (int k = 0; k < K_; ++k) {
        const float* g = xb + (size_t)id[k] * D_;
        float s = bias[o];
        for (int d = 0; d < D_; ++d)
            s += (g[d] - c[d]) * w1[d] + c[d] * w2[d];
        best = fmaxf(best, s);
    }
    out[t] = best > 0.0f ? best : 0.0f;
}

extern "C" void kernel_launch(void* const* d_in, const int* in_sizes, int n_in,
                              void* d_out, int out_size, void* d_ws, size_t ws_size,
                              hipStream_t stream) {
    const float* x    = (const float*)d_in[0];
    const float* xs   = (const float*)d_in[1];
    const int*   idx  = (const int*)d_in[2];
    const float* W    = (const float*)d_in[3];
    const float* bias = (const float*)d_in[4];
    float* out = (float*)d_out;

    const size_t needG = (size_t)B_ * N_ * 64 * sizeof(__half);  // 16.78 MB
    const size_t needC = (size_t)B_ * M_ * 64 * sizeof(__half);  //  4.19 MB

    if (ws_size < needG + needC) {
        size_t total = (size_t)B_ * O_ * M_;
        naive_all<<<(int)((total + 255) / 256), 256, 0, stream>>>(x, xs, idx, W, bias, out);
        return;
    }

    __half* G = (__half*)d_ws;
    __half* C = (__half*)((char*)d_ws + needG);

    // jobs: 2048 G-jobs + 512 C-jobs, 4 waves/block
    gemm_gc<<<640, 256, 0, stream>>>(x, xs, W, bias, G, C);
    gather_max<<<(B_ * M_) / 32, 256, 0, stream>>>(idx, G, C, out);
}

// Round 4
// 47.967 us; speedup vs baseline: 1.6826x; 1.2460x over previous
//
#include <hip/hip_runtime.h>
#include <hip/hip_fp16.h>
#include <math.h>

#define B_ 4
#define N_ 32768
#define M_ 8192
#define K_ 16
#define D_ 64
#define O_ 64

typedef __attribute__((ext_vector_type(8))) short bf16x8;
typedef __attribute__((ext_vector_type(4))) float f32x4;

// float -> bf16 bits, round-to-nearest-even (inputs are finite normals)
static __device__ __forceinline__ short f2bf(float f) {
    unsigned u = __float_as_uint(f);
    u += 0x7fffu + ((u >> 16) & 1u);
    return (short)(u >> 16);
}

// ---------------------------------------------------------------------------
// Kernel A (MFMA, no LDS):
//   G[b*N+n][64] fp16 = x-row . W1           (permuted col order: pos p holds
//   C[b*M+m][64] fp16 = xs-row . (W2-W1) + b  o = (p&3)*16 + (p>>2))
// Wave = 32 rows (2 MFMA 16-row tiles). 5120 waves -> 5 waves/SIMD for
// latency hiding (R3 had 2.5). Fragments loaded straight from global in MFMA
// lane layout: lane l -> row (l&15), k-chunk (l>>4)*8.
// ---------------------------------------------------------------------------
__global__ __launch_bounds__(256)
void gemm_gc(const float* __restrict__ x, const float* __restrict__ xs,
             const float* __restrict__ W, const float* __restrict__ bias,
             __half* __restrict__ G, __half* __restrict__ C) {
    const int tid = threadIdx.x;
    const int l   = tid & 63;
    const int lr  = l & 15;          // A-row / B-col within tile
    const int kg  = l >> 4;          // k-group (8 consecutive k each)
    const int job = blockIdx.x * 4 + (tid >> 6);     // 0..5119, 32 rows each
    const bool cmode = job >= (B_ * N_) / 32;        // jobs 4096..5119

    // ---- B fragments: bf[s][t] covers k = s*32 + kg*8 + 0..7, o = t*16 + lr
    bf16x8 bf[2][4];
    float  binit[4] = {0.f, 0.f, 0.f, 0.f};
    #pragma unroll
    for (int t = 0; t < 4; ++t) {
        #pragma unroll
        for (int s = 0; s < 2; ++s) {
            const float* wp = W + (size_t)(t * 16 + lr) * 128 + s * 32 + kg * 8;
            float4 f0 = *(const float4*)wp;
            float4 f1 = *(const float4*)(wp + 4);
            if (cmode) {
                float4 g0 = *(const float4*)(wp + 64);
                float4 g1 = *(const float4*)(wp + 68);
                f0.x = g0.x - f0.x; f0.y = g0.y - f0.y;
                f0.z = g0.z - f0.z; f0.w = g0.w - f0.w;
                f1.x = g1.x - f1.x; f1.y = g1.y - f1.y;
                f1.z = g1.z - f1.z; f1.w = g1.w - f1.w;
            }
            bf16x8 v;
            v[0] = f2bf(f0.x); v[1] = f2bf(f0.y); v[2] = f2bf(f0.z); v[3] = f2bf(f0.w);
            v[4] = f2bf(f1.x); v[5] = f2bf(f1.y); v[6] = f2bf(f1.z); v[7] = f2bf(f1.w);
            bf[s][t] = v;
        }
    }
    if (cmode) {
        #pragma unroll
        for (int t = 0; t < 4; ++t) binit[t] = bias[t * 16 + lr];
    }

    const long rows0 = (cmode ? (long)(job - (B_ * N_) / 32) : (long)job) * 32;
    const float* src = cmode ? xs : x;
    __half* dst = cmode ? C : G;

    #pragma unroll
    for (int i = 0; i < 2; ++i) {
        const long r0 = rows0 + i * 16;

        // A fragments for this 16-row tile
        bf16x8 af[2];
        #pragma unroll
        for (int s = 0; s < 2; ++s) {
            const float* xp = src + (size_t)(r0 + lr) * 64 + s * 32 + kg * 8;
            float4 f0 = *(const float4*)xp;
            float4 f1 = *(const float4*)(xp + 4);
            bf16x8 v;
            v[0] = f2bf(f0.x); v[1] = f2bf(f0.y); v[2] = f2bf(f0.z); v[3] = f2bf(f0.w);
            v[4] = f2bf(f1.x); v[5] = f2bf(f1.y); v[6] = f2bf(f1.z); v[7] = f2bf(f1.w);
            af[s] = v;
        }

        f32x4 acc[4];
        #pragma unroll
        for (int t = 0; t < 4; ++t) {
            f32x4 a = {binit[t], binit[t], binit[t], binit[t]};
            a = __builtin_amdgcn_mfma_f32_16x16x32_bf16(af[0], bf[0][t], a, 0, 0, 0);
            a = __builtin_amdgcn_mfma_f32_16x16x32_bf16(af[1], bf[1][t], a, 0, 0, 0);
            acc[t] = a;
        }

        // D: lane holds rows (kg*4 + r), col lr, for 4 o-tiles t.
        // Permuted row storage: element index lr*4 + t -> 4 contiguous fp16.
        #pragma unroll
        for (int r = 0; r < 4; ++r) {
            unsigned lo = (unsigned)__half_as_ushort(__float2half(acc[0][r]))
                        | ((unsigned)__half_as_ushort(__float2half(acc[1][r])) << 16);
            unsigned hi = (unsigned)__half_as_ushort(__float2half(acc[2][r]))
                        | ((unsigned)__half_as_ushort(__float2half(acc[3][r])) << 16);
            __half* hp = dst + (size_t)(r0 + kg * 4 + r) * 64 + lr * 4;
            int2 pv; pv.x = (int)lo; pv.y = (int)hi;
            *(int2*)hp = pv;
        }
    }
}

// ---------------------------------------------------------------------------
// Kernel B: 512 threads = 8 waves, block = 32 m of one batch, wave = 4 m.
// idx (2KB/block) staged coalesced into LDS once -> per-m index reads are
// LDS broadcasts, removing the global idx load from the gather chain.
// Lane j gathers G[b, row][j] (2B; wave-load = one full 128B line), max over
// k, + C, relu; transpose via LDS; coalesced float4 stores to out[b][o][m],
// o = (j&3)*16 + (j>>2) un-permutes kernel A's column order.
// ---------------------------------------------------------------------------
__global__ __launch_bounds__(512)
void gather_max(const int* __restrict__ idx, const __half* __restrict__ G,
                const __half* __restrict__ C, float* __restrict__ out) {
    __shared__ int   ldsI[512];        // 32 m x 16 k
    __shared__ float ldsT[64 * 33];
    const int tid = threadIdx.x;
    const int blk = blockIdx.x;          // 0..1023
    const int bb  = blk >> 8;            // 256 blocks per batch
    const int m0  = (blk & 255) * 32;

    ldsI[tid] = idx[((size_t)bb * M_ + m0) * 16 + tid];
    __syncthreads();

    const int j  = tid & 63;
    const int wv = tid >> 6;             // 0..7
    const int o_orig = (j & 3) * 16 + (j >> 2);
    const __half* Gb = G + (size_t)bb * N_ * 64 + j;

    #pragma unroll
    for (int mm = 0; mm < 4; ++mm) {
        const int mloc = wv * 4 + mm;
        int rr[16];
        #pragma unroll
        for (int k4 = 0; k4 < 4; ++k4) {
            int4 q = *(const int4*)&ldsI[mloc * 16 + k4 * 4];
            rr[k4 * 4 + 0] = q.x; rr[k4 * 4 + 1] = q.y;
            rr[k4 * 4 + 2] = q.z; rr[k4 * 4 + 3] = q.w;
        }
        float best = -INFINITY;
        #pragma unroll
        for (int k = 0; k < 16; ++k)
            best = fmaxf(best, __half2float(Gb[(size_t)rr[k] * 64]));
        float cv = __half2float(C[((size_t)bb * M_ + m0 + mloc) * 64 + j]);
        float r = best + cv;
        ldsT[o_orig * 33 + mloc] = r > 0.f ? r : 0.f;
    }
    __syncthreads();

    // out: thread t -> o = t>>3, 4 consecutive m at (t&7)*4
    const int o  = tid >> 3;
    const int ms = (tid & 7) * 4;
    float4 v = make_float4(ldsT[o * 33 + ms + 0], ldsT[o * 33 + ms + 1],
                           ldsT[o * 33 + ms + 2], ldsT[o * 33 + ms + 3]);
    *(float4*)(out + ((size_t)bb * 64 + o) * M_ + m0 + ms) = v;
}

// ---------------------------------------------------------------------------
// Naive exact fallback (only if ws too small).
// ---------------------------------------------------------------------------
__global__ void naive_all(const float* __restrict__ x, const float* __restrict__ xs,
                          const int* __restrict__ idx, const float* __restrict__ W,
                          const float* __restrict__ bias, float* __restrict__ out) {
    size_t t = (size_t)blockIdx.x * 256 + threadIdx.x;
    if (t >= (size_t)B_ * O_ * M_) return;
    int m = (int)(t % M_);
    int o = (int)((t / M_) % O_);
    int b = (int)(t / ((size_t)M_ * O_));
    const float* xb = x + (size_t)b * N_ * D_;
    const float* c  = xs + ((size_t)b * M_ + m) * D_;
    const int*   id = idx + ((size_t)b * M_ + m) * K_;
    const float* w1 = W + o * 128;
    const float* w2 = w1 + 64;
    float best = -INFINITY;
    for (int k = 0; k < K_; ++k) {
        const float* g = xb + (size_t)id[k] * D_;
        float s = bias[o];
        for (int d = 0; d < D_; ++d)
            s += (g[d] - c[d]) * w1[d] + c[d] * w2[d];
        best = fmaxf(best, s);
    }
    out[t] = best > 0.0f ? best : 0.0f;
}

extern "C" void kernel_launch(void* const* d_in, const int* in_sizes, int n_in,
                              void* d_out, int out_size, void* d_ws, size_t ws_size,
                              hipStream_t stream) {
    const float* x    = (const float*)d_in[0];
    const float* xs   = (const float*)d_in[1];
    const int*   idx  = (const int*)d_in[2];
    const float* W    = (const float*)d_in[3];
    const float* bias = (const float*)d_in[4];
    float* out = (float*)d_out;

    const size_t needG = (size_t)B_ * N_ * 64 * sizeof(__half);  // 16.78 MB
    const size_t needC = (size_t)B_ * M_ * 64 * sizeof(__half);  //  4.19 MB

    if (ws_size < needG + needC) {
        size_t total = (size_t)B_ * O_ * M_;
        naive_all<<<(int)((total + 255) / 256), 256, 0, stream>>>(x, xs, idx, W, bias, out);
        return;
    }

    __half* G = (__half*)d_ws;
    __half* C = (__half*)((char*)d_ws + needG);

    // 5120 jobs of 32 rows (4096 G + 1024 C), 4 waves/block
    gemm_gc<<<1280, 256, 0, stream>>>(x, xs, W, bias, G, C);
    // 1024 blocks x 512 threads, 32 m per block
    gather_max<<<(B_ * M_) / 32, 512, 0, stream>>>(idx, G, C, out);
}

// Round 5
// 47.647 us; speedup vs baseline: 1.6939x; 1.0067x over previous
//
#include <hip/hip_runtime.h>
#include <hip/hip_fp16.h>
#include <math.h>

#define B_ 4
#define N_ 32768
#define M_ 8192
#define K_ 16
#define D_ 64
#define O_ 64

typedef __attribute__((ext_vector_type(8))) short bf16x8;
typedef __attribute__((ext_vector_type(4))) float f32x4;

// float -> bf16 bits, round-to-nearest-even (inputs are finite normals)
static __device__ __forceinline__ short f2bf(float f) {
    unsigned u = __float_as_uint(f);
    u += 0x7fffu + ((u >> 16) & 1u);
    return (short)(u >> 16);
}

// ---------------------------------------------------------------------------
// Kernel A (MFMA, no LDS) — unchanged from R4:
//   G[b*N+n][64] fp16 = x-row . W1           (permuted col order: pos p holds
//   C[b*M+m][64] fp16 = xs-row . (W2-W1) + b  o = (p&3)*16 + (p>>2))
// Wave = 32 rows (2 MFMA 16-row tiles), 5120 waves (5/SIMD).
// ---------------------------------------------------------------------------
__global__ __launch_bounds__(256)
void gemm_gc(const float* __restrict__ x, const float* __restrict__ xs,
             const float* __restrict__ W, const float* __restrict__ bias,
             __half* __restrict__ G, __half* __restrict__ C) {
    const int tid = threadIdx.x;
    const int l   = tid & 63;
    const int lr  = l & 15;          // A-row / B-col within tile
    const int kg  = l >> 4;          // k-group (8 consecutive k each)
    const int job = blockIdx.x * 4 + (tid >> 6);     // 0..5119, 32 rows each
    const bool cmode = job >= (B_ * N_) / 32;        // jobs 4096..5119

    // ---- B fragments: bf[s][t] covers k = s*32 + kg*8 + 0..7, o = t*16 + lr
    bf16x8 bf[2][4];
    float  binit[4] = {0.f, 0.f, 0.f, 0.f};
    #pragma unroll
    for (int t = 0; t < 4; ++t) {
        #pragma unroll
        for (int s = 0; s < 2; ++s) {
            const float* wp = W + (size_t)(t * 16 + lr) * 128 + s * 32 + kg * 8;
            float4 f0 = *(const float4*)wp;
            float4 f1 = *(const float4*)(wp + 4);
            if (cmode) {
                float4 g0 = *(const float4*)(wp + 64);
                float4 g1 = *(const float4*)(wp + 68);
                f0.x = g0.x - f0.x; f0.y = g0.y - f0.y;
                f0.z = g0.z - f0.z; f0.w = g0.w - f0.w;
                f1.x = g1.x - f1.x; f1.y = g1.y - f1.y;
                f1.z = g1.z - f1.z; f1.w = g1.w - f1.w;
            }
            bf16x8 v;
            v[0] = f2bf(f0.x); v[1] = f2bf(f0.y); v[2] = f2bf(f0.z); v[3] = f2bf(f0.w);
            v[4] = f2bf(f1.x); v[5] = f2bf(f1.y); v[6] = f2bf(f1.z); v[7] = f2bf(f1.w);
            bf[s][t] = v;
        }
    }
    if (cmode) {
        #pragma unroll
        for (int t = 0; t < 4; ++t) binit[t] = bias[t * 16 + lr];
    }

    const long rows0 = (cmode ? (long)(job - (B_ * N_) / 32) : (long)job) * 32;
    const float* src = cmode ? xs : x;
    __half* dst = cmode ? C : G;

    #pragma unroll
    for (int i = 0; i < 2; ++i) {
        const long r0 = rows0 + i * 16;

        bf16x8 af[2];
        #pragma unroll
        for (int s = 0; s < 2; ++s) {
            const float* xp = src + (size_t)(r0 + lr) * 64 + s * 32 + kg * 8;
            float4 f0 = *(const float4*)xp;
            float4 f1 = *(const float4*)(xp + 4);
            bf16x8 v;
            v[0] = f2bf(f0.x); v[1] = f2bf(f0.y); v[2] = f2bf(f0.z); v[3] = f2bf(f0.w);
            v[4] = f2bf(f1.x); v[5] = f2bf(f1.y); v[6] = f2bf(f1.z); v[7] = f2bf(f1.w);
            af[s] = v;
        }

        f32x4 acc[4];
        #pragma unroll
        for (int t = 0; t < 4; ++t) {
            f32x4 a = {binit[t], binit[t], binit[t], binit[t]};
            a = __builtin_amdgcn_mfma_f32_16x16x32_bf16(af[0], bf[0][t], a, 0, 0, 0);
            a = __builtin_amdgcn_mfma_f32_16x16x32_bf16(af[1], bf[1][t], a, 0, 0, 0);
            acc[t] = a;
        }

        // D: lane holds rows (kg*4 + r), col lr, for 4 o-tiles t.
        // Permuted row storage: element index lr*4 + t -> 4 contiguous fp16.
        #pragma unroll
        for (int r = 0; r < 4; ++r) {
            unsigned lo = (unsigned)__half_as_ushort(__float2half(acc[0][r]))
                        | ((unsigned)__half_as_ushort(__float2half(acc[1][r])) << 16);
            unsigned hi = (unsigned)__half_as_ushort(__float2half(acc[2][r]))
                        | ((unsigned)__half_as_ushort(__float2half(acc[3][r])) << 16);
            __half* hp = dst + (size_t)(r0 + kg * 4 + r) * 64 + lr * 4;
            int2 pv; pv.x = (int)lo; pv.y = (int)hi;
            *(int2*)hp = pv;
        }
    }
}

// ---------------------------------------------------------------------------
// Kernel B: 512 threads = 8 waves, block = 32 m of one batch, wave = 4 m.
// NEW (R5): batch-affine XCD swizzle — XCD pair {2c,2c+1} serves only batch c
// so the per-XCD gather working set is one G-batch (4.2 MB ~ L2) instead of
// all four (16.8 MB -> thrash). Bijective over the 1024 blocks.
// idx staged in LDS; lane j gathers G[b,row][j] (one full 128B line per
// (m,k) wave-load); max over k, +C, relu; LDS transpose; coalesced stores.
// o = (j&3)*16 + (j>>2) un-permutes kernel A's column order.
// ---------------------------------------------------------------------------
__global__ __launch_bounds__(512)
void gather_max(const int* __restrict__ idx, const __half* __restrict__ G,
                const __half* __restrict__ C, float* __restrict__ out) {
    __shared__ int   ldsI[512];        // 32 m x 16 k
    __shared__ float ldsT[64 * 33];
    const int tid = threadIdx.x;
    const int blk = blockIdx.x;          // 0..1023
    const int xcd  = blk & 7;            // assumed HW mapping: blk % 8 -> XCD
    const int slot = blk >> 3;            // 0..127
    const int bb   = xcd >> 1;            // batch c on XCD pair {2c, 2c+1}
    const int m0   = ((((xcd & 1) << 7) + slot) << 5);  // m-tile * 32

    ldsI[tid] = idx[((size_t)bb * M_ + m0) * 16 + tid];
    __syncthreads();

    const int j  = tid & 63;
    const int wv = tid >> 6;             // 0..7
    const int o_orig = (j & 3) * 16 + (j >> 2);
    const __half* Gb = G + (size_t)bb * N_ * 64 + j;

    #pragma unroll
    for (int mm = 0; mm < 4; ++mm) {
        const int mloc = wv * 4 + mm;
        int rr[16];
        #pragma unroll
        for (int k4 = 0; k4 < 4; ++k4) {
            int4 q = *(const int4*)&ldsI[mloc * 16 + k4 * 4];
            rr[k4 * 4 + 0] = q.x; rr[k4 * 4 + 1] = q.y;
            rr[k4 * 4 + 2] = q.z; rr[k4 * 4 + 3] = q.w;
        }
        float best = -INFINITY;
        #pragma unroll
        for (int k = 0; k < 16; ++k)
            best = fmaxf(best, __half2float(Gb[(size_t)rr[k] * 64]));
        float cv = __half2float(C[((size_t)bb * M_ + m0 + mloc) * 64 + j]);
        float r = best + cv;
        ldsT[o_orig * 33 + mloc] = r > 0.f ? r : 0.f;
    }
    __syncthreads();

    // out: thread t -> o = t>>3, 4 consecutive m at (t&7)*4
    const int o  = tid >> 3;
    const int ms = (tid & 7) * 4;
    float4 v = make_float4(ldsT[o * 33 + ms + 0], ldsT[o * 33 + ms + 1],
                           ldsT[o * 33 + ms + 2], ldsT[o * 33 + ms + 3]);
    *(float4*)(out + ((size_t)bb * 64 + o) * M_ + m0 + ms) = v;
}

// ---------------------------------------------------------------------------
// Naive exact fallback (only if ws too small).
// ---------------------------------------------------------------------------
__global__ void naive_all(const float* __restrict__ x, const float* __restrict__ xs,
                          const int* __restrict__ idx, const float* __restrict__ W,
                          const float* __restrict__ bias, float* __restrict__ out) {
    size_t t = (size_t)blockIdx.x * 256 + threadIdx.x;
    if (t >= (size_t)B_ * O_ * M_) return;
    int m = (int)(t % M_);
    int o = (int)((t / M_) % O_);
    int b = (int)(t / ((size_t)M_ * O_));
    const float* xb = x + (size_t)b * N_ * D_;
    const float* c  = xs + ((size_t)b * M_ + m) * D_;
    const int*   id = idx + ((size_t)b * M_ + m) * K_;
    const float* w1 = W + o * 128;
    const float* w2 = w1 + 64;
    float best = -INFINITY;
    for (int k = 0; k < K_; ++k) {
        const float* g = xb + (size_t)id[k] * D_;
        float s = bias[o];
        for (int d = 0; d < D_; ++d)
            s += (g[d] - c[d]) * w1[d] + c[d] * w2[d];
        best = fmaxf(best, s);
    }
    out[t] = best > 0.0f ? best : 0.0f;
}

extern "C" void kernel_launch(void* const* d_in, const int* in_sizes, int n_in,
                              void* d_out, int out_size, void* d_ws, size_t ws_size,
                              hipStream_t stream) {
    const float* x    = (const float*)d_in[0];
    const float* xs   = (const float*)d_in[1];
    const int*   idx  = (const int*)d_in[2];
    const float* W    = (const float*)d_in[3];
    const float* bias = (const float*)d_in[4];
    float* out = (float*)d_out;

    const size_t needG = (size_t)B_ * N_ * 64 * sizeof(__half);  // 16.78 MB
    const size_t needC = (size_t)B_ * M_ * 64 * sizeof(__half);  //  4.19 MB

    if (ws_size < needG + needC) {
        size_t total = (size_t)B_ * O_ * M_;
        naive_all<<<(int)((total + 255) / 256), 256, 0, stream>>>(x, xs, idx, W, bias, out);
        return;
    }

    __half* G = (__half*)d_ws;
    __half* C = (__half*)((char*)d_ws + needG);

    // 5120 jobs of 32 rows (4096 G + 1024 C), 4 waves/block
    gemm_gc<<<1280, 256, 0, stream>>>(x, xs, W, bias, G, C);
    // 1024 blocks x 512 threads, 32 m per block, batch-affine XCD swizzle
    gather_max<<<(B_ * M_) / 32, 512, 0, stream>>>(idx, G, C, out);
}